// Round 1
// baseline (925.535 us; speedup 1.0000x reference)
//
#include <hip/hip_runtime.h>

// RGCN, 3 layers. N=100000 nodes, E=1.6M edges, R=16 relations, HID=64.
// Strategy: build CSR by dst once; per layer, fused kernel aggregates
// per-(node,relation) sums H into LDS (bf16) and does out = [H|x] @ Wcat
// via mfma_f32_16x16x32_bf16 (K = 16*64 + 64 = 1088).

#define HID   64
#define NREL  16
#define KD    1088          // NREL*HID + HID (root term appended as extra K)
#define NPB   16            // nodes per block (= MFMA M)
#define LSTR  1096          // LDS row stride in bf16 elems (pad 1088 -> 1096)

typedef __attribute__((ext_vector_type(8))) short bf16x8;
typedef __attribute__((ext_vector_type(4))) float f32x4;
typedef unsigned short us16;
typedef unsigned int u32;

__device__ __forceinline__ float b2f(us16 u) {
    union { u32 i; float f; } c; c.i = ((u32)u) << 16; return c.f;
}
__device__ __forceinline__ us16 f2b(float f) {   // round-to-nearest-even
    union { float f; u32 i; } c; c.f = f;
    u32 x = c.i;
    return (us16)((x + 0x7FFFu + ((x >> 16) & 1u)) >> 16);
}

// ---------- setup kernels (run every call; same work every call) ----------

__global__ void count_kernel(const int* __restrict__ ei, const int* __restrict__ et,
                             int* __restrict__ counts16, int* __restrict__ deg, int E) {
    int e = blockIdx.x * 256 + threadIdx.x;
    if (e < E) {
        int dst = ei[E + e];           // edge_index[1][e]
        int t   = et[e];
        atomicAdd(&counts16[dst * NREL + t], 1);
        atomicAdd(&deg[dst], 1);
    }
}

__global__ __launch_bounds__(1024) void scan1(const int* __restrict__ deg,
                                              int* __restrict__ row_ptr,
                                              int* __restrict__ sums, int N) {
    __shared__ int s[1024];
    int t = threadIdx.x, g = blockIdx.x * 1024 + t;
    int v = (g < N) ? deg[g] : 0;
    s[t] = v; __syncthreads();
    for (int off = 1; off < 1024; off <<= 1) {
        int tv = (t >= off) ? s[t - off] : 0;
        __syncthreads();
        s[t] += tv;
        __syncthreads();
    }
    if (g < N) row_ptr[g] = s[t] - v;          // exclusive scan within block
    if (t == 1023) sums[blockIdx.x] = s[1023]; // block total
}

__global__ void scan2(int* __restrict__ sums, int nb) {  // 1 block, 128 threads
    __shared__ int s[128];
    int t = threadIdx.x;
    int v = (t < nb) ? sums[t] : 0;
    s[t] = v; __syncthreads();
    for (int off = 1; off < 128; off <<= 1) {
        int tv = (t >= off) ? s[t - off] : 0;
        __syncthreads();
        s[t] += tv;
        __syncthreads();
    }
    if (t < nb) sums[t] = s[t] - v;            // exclusive block offsets
}

__global__ __launch_bounds__(1024) void scan3(int* __restrict__ row_ptr,
                                              const int* __restrict__ sums,
                                              int* __restrict__ cursor, int N) {
    int g = blockIdx.x * 1024 + threadIdx.x;
    if (g < N) {
        int v = row_ptr[g] + sums[blockIdx.x];
        row_ptr[g] = v;
        cursor[g]  = v;
    }
}

__global__ void place_kernel(const int* __restrict__ ei, const int* __restrict__ et,
                             const int* __restrict__ counts16, int* __restrict__ cursor,
                             int* __restrict__ src_et, float* __restrict__ w_srt, int E) {
    int e = blockIdx.x * 256 + threadIdx.x;
    if (e < E) {
        int src = ei[e], dst = ei[E + e], t = et[e];
        int pos = atomicAdd(&cursor[dst], 1);
        src_et[pos] = src | (t << 20);         // src < 2^20, t < 16
        w_srt[pos]  = 1.0f / (float)counts16[dst * NREL + t];
    }
}

__global__ void convx_kernel(const float* __restrict__ x, us16* __restrict__ xb, int n4) {
    int i = blockIdx.x * 256 + threadIdx.x;    // n4 = N*HID/4
    if (i < n4) {
        float4 v = ((const float4*)x)[i];
        us16* o = xb + i * 4;
        o[0] = f2b(v.x); o[1] = f2b(v.y); o[2] = f2b(v.z); o[3] = f2b(v.w);
    }
}

// WcatT[l][h][k], k = r*64+d for k<1024, else root d = k-1024.  bf16.
__global__ void convw_kernel(const float* __restrict__ W, const float* __restrict__ Wroot,
                             us16* __restrict__ WcatT, int total, int L) {
    int i = blockIdx.x * 256 + threadIdx.x;    // total = L*HID*KD
    if (i < total) {
        int l = i / (HID * KD);
        int rem = i % (HID * KD);
        int h = rem / KD, k = rem % KD;
        float v;
        if (k < NREL * HID) {
            int r = k >> 6, d = k & 63;
            v = W[(((size_t)l * NREL + r) * HID + d) * HID + h];
        } else {
            int d = k - NREL * HID;
            v = Wroot[((size_t)l * HID + d) * HID + h];
        }
        WcatT[i] = f2b(v);
    }
}

// ---------- fused layer kernel ----------
// Block: 256 threads (4 waves), handles NPB=16 nodes.
// Phase 1: each wave aggregates 4 nodes' edges into LDS H (bf16).
// Phase 2: wave w computes output cols [16w,16w+16) via 34x mfma 16x16x32 bf16.

__global__ __launch_bounds__(256) void layer_kernel(
        const us16* __restrict__ x_in,        // bf16 [N,64]
        const int*  __restrict__ row_ptr,
        const int*  __restrict__ deg,
        const int*  __restrict__ src_et,
        const float* __restrict__ w_srt,
        const us16* __restrict__ WcatT,       // bf16 [64][1088] this layer
        const float* __restrict__ bias,       // fp32 [64] this layer
        us16* __restrict__ x_out,             // bf16 [N,64]  (if !last)
        float* __restrict__ out_f32,          // fp32 [N,64]  (if last)
        int flags, int N)                     // flags: 1=relu, 2=last
{
    __shared__ us16 H[NPB * LSTR];
    const int tid = threadIdx.x, wave = tid >> 6, lane = tid & 63;

    u32* H32 = (u32*)H;
    for (int i = tid; i < NPB * LSTR / 2; i += 256) H32[i] = 0;
    __syncthreads();

    const int node0 = blockIdx.x * NPB;

    // ---- phase 1: aggregate ----
    for (int q = 0; q < 4; ++q) {
        int nl = wave * 4 + q, node = node0 + nl;
        if (node >= N) break;
        int start = row_ptr[node], cnt = deg[node];
        us16* Hrow = H + nl * LSTR;
        Hrow[NREL * HID + lane] = x_in[node * HID + lane];   // root/x columns

        int e = 0;
        for (; e + 8 <= cnt; e += 8) {
            int pe[8]; float wv[8]; float xv[8];
            #pragma unroll
            for (int j = 0; j < 8; ++j) pe[j] = src_et[start + e + j];
            #pragma unroll
            for (int j = 0; j < 8; ++j) wv[j] = w_srt[start + e + j];
            #pragma unroll
            for (int j = 0; j < 8; ++j)
                xv[j] = b2f(x_in[(pe[j] & 0xFFFFF) * HID + lane]);
            #pragma unroll
            for (int j = 0; j < 8; ++j) {
                int a = ((pe[j] >> 20) << 6) + lane;
                Hrow[a] = f2b(b2f(Hrow[a]) + wv[j] * xv[j]);
            }
        }
        for (; e < cnt; ++e) {
            int pe = src_et[start + e];
            float w = w_srt[start + e];
            float x = b2f(x_in[(pe & 0xFFFFF) * HID + lane]);
            int a = ((pe >> 20) << 6) + lane;
            Hrow[a] = f2b(b2f(Hrow[a]) + w * x);
        }
    }
    __syncthreads();

    // ---- phase 2: [H|x] @ Wcat ----
    const int n16 = lane & 15, quad = lane >> 4;
    f32x4 acc = {0.f, 0.f, 0.f, 0.f};
    const us16* Abase = H + n16 * LSTR + quad * 8;                 // A[m][k]
    const us16* Bbase = WcatT + (size_t)(wave * 16 + n16) * KD + quad * 8; // B[k][n] (transposed store)
    #pragma unroll 2
    for (int ks = 0; ks < KD / 32; ++ks) {
        bf16x8 af = *(const bf16x8*)(Abase + ks * 32);
        bf16x8 bf = *(const bf16x8*)(Bbase + ks * 32);
        acc = __builtin_amdgcn_mfma_f32_16x16x32_bf16(af, bf, acc, 0, 0, 0);
    }

    int col = wave * 16 + n16;
    float bv = bias[col];
    #pragma unroll
    for (int ri = 0; ri < 4; ++ri) {
        int nl = quad * 4 + ri, node = node0 + nl;   // C/D: col=lane&15, row=quad*4+ri
        if (node < N) {
            float v = acc[ri] + bv;
            if (flags & 1) v = fmaxf(v, 0.f);
            if (flags & 2) out_f32[node * HID + col] = v;
            else           x_out [node * HID + col] = f2b(v);
        }
    }
}

// ---------- host ----------

extern "C" void kernel_launch(void* const* d_in, const int* in_sizes, int n_in,
                              void* d_out, int out_size, void* d_ws, size_t ws_size,
                              hipStream_t stream) {
    const int*   edge_index = (const int*)  d_in[0];
    const int*   edge_type  = (const int*)  d_in[1];
    const float* node_emb   = (const float*)d_in[2];
    const float* W          = (const float*)d_in[3];
    const float* Wroot      = (const float*)d_in[4];
    const float* bias       = (const float*)d_in[5];
    float* out = (float*)d_out;

    const int E = in_sizes[1];
    const int N = in_sizes[2] / HID;
    const int L = in_sizes[5] / HID;

    // workspace carve (all written before read each call)
    char* p = (char*)d_ws;
    size_t off = 0;
    auto carve = [&](size_t bytes) {
        void* q = p + off;
        off = (off + bytes + 255) & ~(size_t)255;
        return q;
    };
    int*   counts16 = (int*)  carve((size_t)N * NREL * 4);
    int*   deg      = (int*)  carve((size_t)N * 4);
    int*   row_ptr  = (int*)  carve((size_t)N * 4);
    int*   cursor   = (int*)  carve((size_t)N * 4);
    int*   sums     = (int*)  carve(128 * 4);
    int*   src_et   = (int*)  carve((size_t)E * 4);
    float* w_srt    = (float*)carve((size_t)E * 4);
    us16*  xb0      = (us16*) carve((size_t)N * HID * 2);
    us16*  xb1      = (us16*) carve((size_t)N * HID * 2);
    us16*  WcatT    = (us16*) carve((size_t)L * HID * KD * 2);
    (void)ws_size; (void)n_in; (void)out_size;

    hipMemsetAsync(counts16, 0, (size_t)N * NREL * 4, stream);
    hipMemsetAsync(deg,      0, (size_t)N * 4,        stream);

    int ge = (E + 255) / 256;
    int nb = (N + 1023) / 1024;
    count_kernel<<<ge, 256, 0, stream>>>(edge_index, edge_type, counts16, deg, E);
    scan1<<<nb, 1024, 0, stream>>>(deg, row_ptr, sums, N);
    scan2<<<1, 128, 0, stream>>>(sums, nb);
    scan3<<<nb, 1024, 0, stream>>>(row_ptr, sums, cursor, N);
    place_kernel<<<ge, 256, 0, stream>>>(edge_index, edge_type, counts16, cursor,
                                         src_et, w_srt, E);
    convx_kernel<<<(N * HID / 4 + 255) / 256, 256, 0, stream>>>(node_emb, xb0, N * HID / 4);
    int wtot = L * HID * KD;
    convw_kernel<<<(wtot + 255) / 256, 256, 0, stream>>>(W, Wroot, WcatT, wtot, L);

    int gl = (N + NPB - 1) / NPB;
    us16* xin = xb0;
    us16* xother = xb1;
    for (int l = 0; l < L; ++l) {
        int last = (l == L - 1);
        int flags = (last ? 2 : 1);
        layer_kernel<<<gl, 256, 0, stream>>>(
            xin, row_ptr, deg, src_et, w_srt,
            WcatT + (size_t)l * HID * KD, bias + (size_t)l * HID,
            last ? nullptr : xother, last ? out : nullptr,
            flags, N);
        us16* t = xin; xin = xother; xother = t;
    }
}

// Round 2
// 838.035 us; speedup vs baseline: 1.1044x; 1.1044x over previous
//
#include <hip/hip_runtime.h>

// RGCN, 3 layers. N=100000, E=1.6M, R=16, HID=64.
// Edges sorted by (dst, rel) via counting sort. Per layer: fused kernel
// aggregates per-(node,rel) means in fp32 registers (run-length segments),
// flushes bf16 to LDS H, then out = [H|x] @ Wcat via mfma_f32_16x16x32_bf16.

#define HID   64
#define NREL  16
#define KD    1088          // NREL*HID + HID (root x appended as extra K)
#define NPB   16            // nodes per block (= MFMA M)
#define LSTR  1096          // LDS row stride (pad 1088 -> 1096: balanced b128 reads)

typedef __attribute__((ext_vector_type(8))) short bf16x8;
typedef __attribute__((ext_vector_type(4))) float f32x4;
typedef unsigned short us16;
typedef unsigned int u32;

__device__ __forceinline__ float b2f(us16 u) {
    union { u32 i; float f; } c; c.i = ((u32)u) << 16; return c.f;
}
__device__ __forceinline__ us16 f2b(float f) {   // round-to-nearest-even
    union { float f; u32 i; } c; c.f = f;
    u32 x = c.i;
    return (us16)((x + 0x7FFFu + ((x >> 16) & 1u)) >> 16);
}

// ---------- setup: counting sort by (dst*16+rel) ----------

__global__ void count_kernel(const int* __restrict__ ei, const int* __restrict__ et,
                             int* __restrict__ counts16, int E) {
    int e = blockIdx.x * 256 + threadIdx.x;
    if (e < E) {
        int dst = ei[E + e];
        int t   = et[e];
        atomicAdd(&counts16[dst * NREL + t], 1);
    }
}

// 4 elems/thread, 4096/block. seg_excl = within-block exclusive prefix.
__global__ __launch_bounds__(1024) void scan1(const int* __restrict__ counts16,
                                              int* __restrict__ seg_excl,
                                              int* __restrict__ sums, int nr16) {
    __shared__ int s[1024];
    int t = threadIdx.x;
    int g4 = (blockIdx.x * 1024 + t) * 4;
    int c0 = 0, c1 = 0, c2 = 0, c3 = 0;
    if (g4 + 3 < nr16) {
        const int4 v = *(const int4*)(counts16 + g4);
        c0 = v.x; c1 = v.y; c2 = v.z; c3 = v.w;
    } else {
        if (g4 + 0 < nr16) c0 = counts16[g4 + 0];
        if (g4 + 1 < nr16) c1 = counts16[g4 + 1];
        if (g4 + 2 < nr16) c2 = counts16[g4 + 2];
        if (g4 + 3 < nr16) c3 = counts16[g4 + 3];
    }
    int loc = c0 + c1 + c2 + c3;
    s[t] = loc; __syncthreads();
    for (int off = 1; off < 1024; off <<= 1) {
        int tv = (t >= off) ? s[t - off] : 0;
        __syncthreads();
        s[t] += tv;
        __syncthreads();
    }
    int ex = s[t] - loc;
    if (g4 + 0 < nr16) seg_excl[g4 + 0] = ex;
    if (g4 + 1 < nr16) seg_excl[g4 + 1] = ex + c0;
    if (g4 + 2 < nr16) seg_excl[g4 + 2] = ex + c0 + c1;
    if (g4 + 3 < nr16) seg_excl[g4 + 3] = ex + c0 + c1 + c2;
    if (t == 1023) sums[blockIdx.x] = s[1023];
}

__global__ void scan2(int* __restrict__ sums, int nb,
                      int* __restrict__ row_ptr, int N, int E) {  // 1 block, 512 thr
    __shared__ int s[512];
    int t = threadIdx.x;
    int v = (t < nb) ? sums[t] : 0;
    s[t] = v; __syncthreads();
    for (int off = 1; off < 512; off <<= 1) {
        int tv = (t >= off) ? s[t - off] : 0;
        __syncthreads();
        s[t] += tv;
        __syncthreads();
    }
    if (t < nb) sums[t] = s[t] - v;
    if (t == 0) row_ptr[N] = E;
}

__global__ __launch_bounds__(1024) void scan3(const int* __restrict__ seg_excl,
                                              const int* __restrict__ sums,
                                              int* __restrict__ cursor16,
                                              int* __restrict__ row_ptr, int nr16) {
    int t = threadIdx.x;
    int g4 = (blockIdx.x * 1024 + t) * 4;
    int add = sums[blockIdx.x];
    #pragma unroll
    for (int j = 0; j < 4; ++j) {
        int g = g4 + j;
        if (g < nr16) {
            int v = seg_excl[g] + add;
            cursor16[g] = v;
            if ((g & 15) == 0) row_ptr[g >> 4] = v;
        }
    }
}

__global__ void place_kernel(const int* __restrict__ ei, const int* __restrict__ et,
                             int* __restrict__ cursor16,
                             int* __restrict__ src_et, int E) {
    int e = blockIdx.x * 256 + threadIdx.x;
    if (e < E) {
        int src = ei[e], dst = ei[E + e], t = et[e];
        int pos = atomicAdd(&cursor16[dst * NREL + t], 1);
        src_et[pos] = src | (t << 20);         // src < 2^20, t < 16
    }
}

__global__ void convx_kernel(const float* __restrict__ x, us16* __restrict__ xb, int n4) {
    int i = blockIdx.x * 256 + threadIdx.x;    // n4 = N*HID/4
    if (i < n4) {
        float4 v = ((const float4*)x)[i];
        us16* o = xb + i * 4;
        o[0] = f2b(v.x); o[1] = f2b(v.y); o[2] = f2b(v.z); o[3] = f2b(v.w);
    }
}

// WcatT[l][h][k], k = r*64+d for k<1024, else root d = k-1024.  bf16.
__global__ void convw_kernel(const float* __restrict__ W, const float* __restrict__ Wroot,
                             us16* __restrict__ WcatT, int total, int L) {
    int i = blockIdx.x * 256 + threadIdx.x;    // total = L*HID*KD
    if (i < total) {
        int l = i / (HID * KD);
        int rem = i % (HID * KD);
        int h = rem / KD, k = rem % KD;
        float v;
        if (k < NREL * HID) {
            int r = k >> 6, d = k & 63;
            v = W[(((size_t)l * NREL + r) * HID + d) * HID + h];
        } else {
            int d = k - NREL * HID;
            v = Wroot[((size_t)l * HID + d) * HID + h];
        }
        WcatT[i] = f2b(v);
    }
}

// ---------- fused layer kernel ----------
// 256 threads (4 waves) per block, NPB=16 nodes. Phase 1: each wave
// aggregates 4 nodes; edges sorted by rel within node -> fp32 register
// accumulation per run, single bf16 LDS write per (node,rel) segment.
// Phase 2: wave w computes output cols [16w,16w+16) via 34x mfma.

__global__ __launch_bounds__(256) void layer_kernel(
        const us16* __restrict__ x_in,        // bf16 [N,64]
        const int*  __restrict__ row_ptr,     // [N+1]
        const int*  __restrict__ src_et,      // sorted by (dst,rel)
        const us16* __restrict__ WcatT,       // bf16 [64][1088] this layer
        const float* __restrict__ bias,       // fp32 [64] this layer
        us16* __restrict__ x_out,             // bf16 [N,64]  (if !last)
        float* __restrict__ out_f32,          // fp32 [N,64]  (if last)
        int flags, int N)                     // flags: 1=relu, 2=last
{
    __shared__ us16 H[NPB * LSTR];
    const int tid = threadIdx.x, wave = tid >> 6, lane = tid & 63;
    const int node0 = blockIdx.x * NPB;

    // ---- phase 1: aggregate ----
    for (int q = 0; q < 4; ++q) {
        int nl = wave * 4 + q, node = node0 + nl;
        if (node >= N) break;
        int start = row_ptr[node], cnt = row_ptr[node + 1] - start;
        us16* Hrow = H + nl * LSTR;
        Hrow[NREL * HID + lane] = x_in[node * HID + lane];   // root/x columns

        float acc = 0.f;
        int runlen = 0, prev = -1;
        u32 mask = 0;

        for (int w0 = 0; w0 < cnt; w0 += 64) {
            int wcnt = min(64, cnt - w0);
            int pe_l = (lane < wcnt) ? src_et[start + w0 + lane] : 0;  // coalesced
            #pragma unroll 1
            for (int c = 0; c < wcnt; c += 8) {
                us16 hv[8]; int rr[8];
                #pragma unroll
                for (int j = 0; j < 8; ++j) {
                    int idx = c + j; if (idx >= wcnt) idx = wcnt - 1;
                    int pe = __shfl(pe_l, idx);
                    rr[j] = pe >> 20;
                    hv[j] = x_in[(pe & 0xFFFFF) * HID + lane];
                }
                int m = min(8, wcnt - c);
                #pragma unroll
                for (int j = 0; j < 8; ++j) {
                    if (j < m) {
                        int r = rr[j];
                        if (r != prev) {
                            if (prev >= 0) {
                                Hrow[(prev << 6) + lane] =
                                    f2b(acc * __builtin_amdgcn_rcpf((float)runlen));
                                mask |= 1u << prev;
                            }
                            prev = r; acc = 0.f; runlen = 0;
                        }
                        acc += b2f(hv[j]); ++runlen;
                    }
                }
            }
        }
        if (prev >= 0) {
            Hrow[(prev << 6) + lane] = f2b(acc * __builtin_amdgcn_rcpf((float)runlen));
            mask |= 1u << prev;
        }
        #pragma unroll
        for (int r = 0; r < NREL; ++r)
            if (!(mask & (1u << r))) Hrow[(r << 6) + lane] = 0;
    }
    __syncthreads();

    // ---- phase 2: [H|x] @ Wcat ----
    const int n16 = lane & 15, quad = lane >> 4;
    f32x4 acc = {0.f, 0.f, 0.f, 0.f};
    const us16* Abase = H + n16 * LSTR + quad * 8;                            // A[m][k]
    const us16* Bbase = WcatT + (size_t)(wave * 16 + n16) * KD + quad * 8;    // B[k][n]^T
    #pragma unroll 2
    for (int ks = 0; ks < KD / 32; ++ks) {
        bf16x8 af = *(const bf16x8*)(Abase + ks * 32);
        bf16x8 bf = *(const bf16x8*)(Bbase + ks * 32);
        acc = __builtin_amdgcn_mfma_f32_16x16x32_bf16(af, bf, acc, 0, 0, 0);
    }

    int col = wave * 16 + n16;
    float bv = bias[col];
    #pragma unroll
    for (int ri = 0; ri < 4; ++ri) {
        int nl = quad * 4 + ri, node = node0 + nl;   // C/D: col=lane&15, row=quad*4+ri
        if (node < N) {
            float v = acc[ri] + bv;
            if (flags & 1) v = fmaxf(v, 0.f);
            if (flags & 2) out_f32[node * HID + col] = v;
            else           x_out [node * HID + col] = f2b(v);
        }
    }
}

// ---------- host ----------

extern "C" void kernel_launch(void* const* d_in, const int* in_sizes, int n_in,
                              void* d_out, int out_size, void* d_ws, size_t ws_size,
                              hipStream_t stream) {
    const int*   edge_index = (const int*)  d_in[0];
    const int*   edge_type  = (const int*)  d_in[1];
    const float* node_emb   = (const float*)d_in[2];
    const float* W          = (const float*)d_in[3];
    const float* Wroot      = (const float*)d_in[4];
    const float* bias       = (const float*)d_in[5];
    float* out = (float*)d_out;

    const int E = in_sizes[1];
    const int N = in_sizes[2] / HID;
    const int L = in_sizes[5] / HID;
    const int NR16 = N * NREL;

    char* p = (char*)d_ws;
    size_t off = 0;
    auto carve = [&](size_t bytes) {
        void* q = p + off;
        off = (off + bytes + 255) & ~(size_t)255;
        return q;
    };
    int*   counts16 = (int*)  carve((size_t)NR16 * 4);
    int*   seg_excl = (int*)  carve((size_t)NR16 * 4);
    int*   cursor16 = (int*)  carve((size_t)NR16 * 4);
    int*   row_ptr  = (int*)  carve((size_t)(N + 1) * 4);
    int*   sums     = (int*)  carve(512 * 4);
    int*   src_et   = (int*)  carve((size_t)E * 4);
    us16*  xb0      = (us16*) carve((size_t)N * HID * 2);
    us16*  xb1      = (us16*) carve((size_t)N * HID * 2);
    us16*  WcatT    = (us16*) carve((size_t)L * HID * KD * 2);
    (void)ws_size; (void)n_in; (void)out_size;

    hipMemsetAsync(counts16, 0, (size_t)NR16 * 4, stream);

    int ge  = (E + 255) / 256;
    int nb4 = (NR16 + 4095) / 4096;     // blocks for 4-elem/thread scans (<=512)
    count_kernel<<<ge, 256, 0, stream>>>(edge_index, edge_type, counts16, E);
    scan1<<<nb4, 1024, 0, stream>>>(counts16, seg_excl, sums, NR16);
    scan2<<<1, 512, 0, stream>>>(sums, nb4, row_ptr, N, E);
    scan3<<<nb4, 1024, 0, stream>>>(seg_excl, sums, cursor16, row_ptr, NR16);
    place_kernel<<<ge, 256, 0, stream>>>(edge_index, edge_type, cursor16, src_et, E);
    convx_kernel<<<(N * HID / 4 + 255) / 256, 256, 0, stream>>>(node_emb, xb0, N * HID / 4);
    int wtot = L * HID * KD;
    convw_kernel<<<(wtot + 255) / 256, 256, 0, stream>>>(W, Wroot, WcatT, wtot, L);

    int gl = (N + NPB - 1) / NPB;
    us16* xin = xb0;
    us16* xother = xb1;
    for (int l = 0; l < L; ++l) {
        int last = (l == L - 1);
        int flags = (last ? 2 : 1);
        layer_kernel<<<gl, 256, 0, stream>>>(
            xin, row_ptr, src_et,
            WcatT + (size_t)l * HID * KD, bias + (size_t)l * HID,
            last ? nullptr : xother, last ? out : nullptr,
            flags, N);
        us16* t = xin; xin = xother; xother = t;
    }
}